// Round 1
// baseline (486.231 us; speedup 1.0000x reference)
//
#include <hip/hip_runtime.h>
#include <hip/hip_bf16.h>
#include <math.h>

#define NIN   256
#define NOUTC 256
#define NHEADS 4
#define NEG   0.2f

// ---------------------------------------------------------------------------
// Kernel 1: h = x @ W   (M x 256) = (M x 256)(256 x 256), fp32 tiled SGEMM
// BM=BN=64, BK=16, 256 threads, 4x4 per thread
// ---------------------------------------------------------------------------
__global__ __launch_bounds__(256) void gemm_h(const float* __restrict__ A,
                                              const float* __restrict__ B,
                                              float* __restrict__ C, int M)
{
    __shared__ float As[16][64];   // [k][m] (transposed A tile)
    __shared__ float Bs[16][64];   // [k][n]
    const int tid = threadIdx.x;
    const int bm = blockIdx.x, bn = blockIdx.y;
    const int tx = tid & 15, ty = tid >> 4;
    const int arow = tid >> 2, acol = (tid & 3) << 2;   // A tile: 64 rows x 16 cols
    const int brow = tid >> 4, bcol = (tid & 15) << 2;  // B tile: 16 rows x 64 cols
    const int grow = bm * 64 + arow;

    float acc[4][4] = {};

    for (int k0 = 0; k0 < 256; k0 += 16) {
        float4 av = make_float4(0.f, 0.f, 0.f, 0.f);
        if (grow < M)
            av = *(const float4*)(A + (size_t)grow * 256 + k0 + acol);
        float4 bv = *(const float4*)(B + (size_t)(k0 + brow) * 256 + bn * 64 + bcol);

        As[acol + 0][arow] = av.x;
        As[acol + 1][arow] = av.y;
        As[acol + 2][arow] = av.z;
        As[acol + 3][arow] = av.w;
        *(float4*)&Bs[brow][bcol] = bv;
        __syncthreads();

#pragma unroll
        for (int kk = 0; kk < 16; ++kk) {
            float4 a4 = *(const float4*)&As[kk][ty << 2];
            float4 b4 = *(const float4*)&Bs[kk][tx << 2];
            float a[4] = {a4.x, a4.y, a4.z, a4.w};
            float b[4] = {b4.x, b4.y, b4.z, b4.w};
#pragma unroll
            for (int i = 0; i < 4; ++i)
#pragma unroll
                for (int j = 0; j < 4; ++j)
                    acc[i][j] = fmaf(a[i], b[j], acc[i][j]);
        }
        __syncthreads();
    }

#pragma unroll
    for (int i = 0; i < 4; ++i) {
        int r = bm * 64 + (ty << 2) + i;
        if (r < M)
            *(float4*)(C + (size_t)r * 256 + bn * 64 + (tx << 2)) =
                make_float4(acc[i][0], acc[i][1], acc[i][2], acc[i][3]);
    }
}

// ---------------------------------------------------------------------------
// Kernel 2: per-node attention projections a_src[n][h], a_dst[n][h]
// 4 nodes per 256-thread block (one wave each)
// ---------------------------------------------------------------------------
__global__ __launch_bounds__(256) void attn_proj(const float* __restrict__ h,
                                                 const float* __restrict__ att_src,
                                                 const float* __restrict__ att_dst,
                                                 float* __restrict__ a_src_n,
                                                 float* __restrict__ a_dst_n, int N)
{
    const int wv = threadIdx.x >> 6;
    const int l  = threadIdx.x & 63;
    const int n  = blockIdx.x * 4 + wv;
    if (n >= N) return;
    const float* hr = h + (size_t)n * 256;

    float h0 = hr[l], h1 = hr[64 + l], h2 = hr[128 + l], h3 = hr[192 + l];
    float ps0 = h0 * att_src[l];
    float ps1 = h1 * att_src[64 + l];
    float ps2 = h2 * att_src[128 + l];
    float ps3 = h3 * att_src[192 + l];
    float pd0 = h0 * att_dst[l];
    float pd1 = h1 * att_dst[64 + l];
    float pd2 = h2 * att_dst[128 + l];
    float pd3 = h3 * att_dst[192 + l];

#pragma unroll
    for (int o = 32; o > 0; o >>= 1) {
        ps0 += __shfl_xor(ps0, o); ps1 += __shfl_xor(ps1, o);
        ps2 += __shfl_xor(ps2, o); ps3 += __shfl_xor(ps3, o);
        pd0 += __shfl_xor(pd0, o); pd1 += __shfl_xor(pd1, o);
        pd2 += __shfl_xor(pd2, o); pd3 += __shfl_xor(pd3, o);
    }
    if (l == 0) {
        a_src_n[4 * n + 0] = ps0; a_src_n[4 * n + 1] = ps1;
        a_src_n[4 * n + 2] = ps2; a_src_n[4 * n + 3] = ps3;
        a_dst_n[4 * n + 0] = pd0; a_dst_n[4 * n + 1] = pd1;
        a_dst_n[4 * n + 2] = pd2; a_dst_n[4 * n + 3] = pd3;
    }
}

// ---------------------------------------------------------------------------
// Kernel 3: degree histogram over dst (edges + self loops)
// ---------------------------------------------------------------------------
__global__ void hist_kernel(const int* __restrict__ ei, int* __restrict__ deg,
                            int E, int N)
{
    int e = blockIdx.x * 256 + threadIdx.x;
    if (e >= E + N) return;
    int dte = (e < E) ? ei[E + e] : (e - E);
    atomicAdd(&deg[dte], 1);
}

// ---------------------------------------------------------------------------
// Kernel 4: exclusive prefix sum over deg[N] -> off[N+1], cur[N]
// single block, 1024 threads, wave-shfl two-level scan
// ---------------------------------------------------------------------------
__global__ __launch_bounds__(1024) void scan_kernel(const int* __restrict__ deg,
                                                    int* __restrict__ off,
                                                    int* __restrict__ cur, int N)
{
    __shared__ int wsum[16];
    __shared__ int wexc[16];
    const int t = threadIdx.x, lane = t & 63, w = t >> 6;
    int carry = 0;
    for (int base = 0; base < N; base += 1024) {
        int idx = base + t;
        int v = (idx < N) ? deg[idx] : 0;
        int val = v;
#pragma unroll
        for (int o = 1; o < 64; o <<= 1) {
            int u = __shfl_up(val, o);
            if (lane >= o) val += u;
        }
        if (lane == 63) wsum[w] = val;
        __syncthreads();
        if (t < 16) {
            int s = wsum[t];
#pragma unroll
            for (int o = 1; o < 16; o <<= 1) {
                int u = __shfl_up(s, o, 16);
                if (t >= o) s += u;
            }
            wexc[t] = s - wsum[t];
        }
        __syncthreads();
        int excl = carry + wexc[w] + (val - v);
        if (idx < N) { off[idx] = excl; cur[idx] = excl; }
        carry += wexc[15] + wsum[15];
        __syncthreads();
    }
    if (t == 0) off[N] = carry;
}

// ---------------------------------------------------------------------------
// Kernel 5: scatter edges into CSR by dst
// ---------------------------------------------------------------------------
__global__ void scatter_kernel(const int* __restrict__ ei, int* __restrict__ cur,
                               int* __restrict__ csr, int E, int N)
{
    int e = blockIdx.x * 256 + threadIdx.x;
    if (e >= E + N) return;
    int s, dte;
    if (e < E) { s = ei[e]; dte = ei[E + e]; }
    else       { s = e - E; dte = s; }
    int pos = atomicAdd(&cur[dte], 1);
    csr[pos] = s;
}

// ---------------------------------------------------------------------------
// Kernel 6: per-dst segment softmax + weighted aggregation + bias + relu
// one wave per destination node; lane l owns channels 4l..4l+3 (head = l/16)
// ---------------------------------------------------------------------------
__global__ __launch_bounds__(256) void aggregate(const float* __restrict__ h,
                                                 const float* __restrict__ a_src_n,
                                                 const float* __restrict__ a_dst_n,
                                                 const int* __restrict__ off,
                                                 const int* __restrict__ csr,
                                                 const float* __restrict__ bias,
                                                 float* __restrict__ out, int N)
{
    const int wv = threadIdx.x >> 6;
    const int lane = threadIdx.x & 63;
    const int n = blockIdx.x * 4 + wv;
    if (n >= N) return;

    const int base = off[n];
    const int d = off[n + 1] - base;
    const float4 ad = *(const float4*)(a_dst_n + 4 * n);

    // Phase A: per-head max of leaky(logit)
    float4 m = make_float4(-1e30f, -1e30f, -1e30f, -1e30f);
    for (int j = lane; j < d; j += 64) {
        int s = csr[base + j];
        float4 as = *(const float4*)(a_src_n + 4 * s);
        float lx = as.x + ad.x; lx = lx >= 0.f ? lx : NEG * lx;
        float ly = as.y + ad.y; ly = ly >= 0.f ? ly : NEG * ly;
        float lz = as.z + ad.z; lz = lz >= 0.f ? lz : NEG * lz;
        float lw = as.w + ad.w; lw = lw >= 0.f ? lw : NEG * lw;
        m.x = fmaxf(m.x, lx); m.y = fmaxf(m.y, ly);
        m.z = fmaxf(m.z, lz); m.w = fmaxf(m.w, lw);
    }
#pragma unroll
    for (int o = 32; o > 0; o >>= 1) {
        m.x = fmaxf(m.x, __shfl_xor(m.x, o));
        m.y = fmaxf(m.y, __shfl_xor(m.y, o));
        m.z = fmaxf(m.z, __shfl_xor(m.z, o));
        m.w = fmaxf(m.w, __shfl_xor(m.w, o));
    }

    // Phase B: sum of exp
    float4 sm = make_float4(0.f, 0.f, 0.f, 0.f);
    for (int j = lane; j < d; j += 64) {
        int s = csr[base + j];
        float4 as = *(const float4*)(a_src_n + 4 * s);
        float lx = as.x + ad.x; lx = lx >= 0.f ? lx : NEG * lx;
        float ly = as.y + ad.y; ly = ly >= 0.f ? ly : NEG * ly;
        float lz = as.z + ad.z; lz = lz >= 0.f ? lz : NEG * lz;
        float lw = as.w + ad.w; lw = lw >= 0.f ? lw : NEG * lw;
        sm.x += __expf(lx - m.x); sm.y += __expf(ly - m.y);
        sm.z += __expf(lz - m.z); sm.w += __expf(lw - m.w);
    }
#pragma unroll
    for (int o = 32; o > 0; o >>= 1) {
        sm.x += __shfl_xor(sm.x, o);
        sm.y += __shfl_xor(sm.y, o);
        sm.z += __shfl_xor(sm.z, o);
        sm.w += __shfl_xor(sm.w, o);
    }
    float4 inv = make_float4(1.f / (sm.x + 1e-16f), 1.f / (sm.y + 1e-16f),
                             1.f / (sm.z + 1e-16f), 1.f / (sm.w + 1e-16f));

    // per-lane head-scalar state
    const int hl = lane >> 4;
    const float mh  = hl == 0 ? m.x  : hl == 1 ? m.y  : hl == 2 ? m.z  : m.w;
    const float ih  = hl == 0 ? inv.x: hl == 1 ? inv.y: hl == 2 ? inv.z: inv.w;
    const float adh = hl == 0 ? ad.x : hl == 1 ? ad.y : hl == 2 ? ad.z : ad.w;

    // Phase C: weighted accumulate of h[src] rows (coalesced 16B/lane)
    float4 acc = make_float4(0.f, 0.f, 0.f, 0.f);
    const float4* hp = (const float4*)h;
    for (int j = 0; j < d; ++j) {
        int s = csr[base + j];
        float asv = a_src_n[4 * s + hl];
        float lg = asv + adh; lg = lg >= 0.f ? lg : NEG * lg;
        float wgt = __expf(lg - mh) * ih;
        float4 hv = hp[(size_t)s * 64 + lane];
        acc.x = fmaf(wgt, hv.x, acc.x);
        acc.y = fmaf(wgt, hv.y, acc.y);
        acc.z = fmaf(wgt, hv.z, acc.z);
        acc.w = fmaf(wgt, hv.w, acc.w);
    }

    float4 b4 = *(const float4*)(bias + 4 * lane);
    float4 o4 = make_float4(fmaxf(acc.x + b4.x, 0.f), fmaxf(acc.y + b4.y, 0.f),
                            fmaxf(acc.z + b4.z, 0.f), fmaxf(acc.w + b4.w, 0.f));
    *(float4*)(out + (size_t)n * 256 + 4 * lane) = o4;
}

// ---------------------------------------------------------------------------
extern "C" void kernel_launch(void* const* d_in, const int* in_sizes, int n_in,
                              void* d_out, int out_size, void* d_ws, size_t ws_size,
                              hipStream_t stream)
{
    const float* x       = (const float*)d_in[0];
    const int*   ei      = (const int*)d_in[1];
    const float* W       = (const float*)d_in[2];
    const float* att_src = (const float*)d_in[3];
    const float* att_dst = (const float*)d_in[4];
    const float* bias    = (const float*)d_in[5];
    float* out = (float*)d_out;

    const int N = in_sizes[0] / NIN;   // 50000
    const int E = in_sizes[1] / 2;     // 800000
    const int tot = E + N;

    // workspace layout (all written before read, every launch)
    float* h       = (float*)d_ws;                 // N*256
    float* a_src_n = h + (size_t)N * NOUTC;        // N*4
    float* a_dst_n = a_src_n + (size_t)N * 4;      // N*4
    int*   deg     = (int*)(a_dst_n + (size_t)N * 4);  // N
    int*   off     = deg + N;                      // N+1
    int*   cur     = off + N + 1;                  // N
    int*   csr     = cur + N;                      // E+N

    hipMemsetAsync(deg, 0, (size_t)N * sizeof(int), stream);

    dim3 gg((N + 63) / 64, 4);
    gemm_h<<<gg, 256, 0, stream>>>(x, W, h, N);
    attn_proj<<<(N + 3) / 4, 256, 0, stream>>>(h, att_src, att_dst, a_src_n, a_dst_n, N);
    hist_kernel<<<(tot + 255) / 256, 256, 0, stream>>>(ei, deg, E, N);
    scan_kernel<<<1, 1024, 0, stream>>>(deg, off, cur, N);
    scatter_kernel<<<(tot + 255) / 256, 256, 0, stream>>>(ei, cur, csr, E, N);
    aggregate<<<(N + 3) / 4, 256, 0, stream>>>(h, a_src_n, a_dst_n, off, csr, bias, out, N);
}

// Round 2
// 322.434 us; speedup vs baseline: 1.5080x; 1.5080x over previous
//
#include <hip/hip_runtime.h>
#include <math.h>

#define NEG 0.2f

typedef __attribute__((ext_vector_type(4))) float f4;
typedef __attribute__((ext_vector_type(8))) short s8;

__device__ __forceinline__ short f2bf(float f) {
    unsigned u = __float_as_uint(f);
    u += 0x7fff + ((u >> 16) & 1);          // round-to-nearest-even
    return (short)(u >> 16);
}
__device__ __forceinline__ float bf2f(unsigned short s) {
    return __uint_as_float(((unsigned)s) << 16);
}

// ---------------------------------------------------------------------------
// Kernel 0: Wt[n][k] = bf16(W[k][n])   (256x256, tiny)
// ---------------------------------------------------------------------------
__global__ void cast_transpose_W(const float* __restrict__ W, short* __restrict__ Wt)
{
    int k = blockIdx.x, n = threadIdx.x;
    Wt[n * 256 + k] = f2bf(W[k * 256 + n]);
}

// ---------------------------------------------------------------------------
// Kernel 1: MFMA GEMM  hb = bf16(x @ W)  [M x 256], fused attention projections.
// 128x128 tile, 4 waves (2x2), 4x4 16x16x32 MFMAs per wave per k-step.
// Wave (wr,wc) owns cols wc*64..+63 of its bn half => exactly one head =>
// a_src/a_dst computed via in-register reduce, no atomics.
// ---------------------------------------------------------------------------
__global__ __launch_bounds__(256) void gemm_attn(
    const float* __restrict__ x, const short* __restrict__ Wt,
    const float* __restrict__ att_src, const float* __restrict__ att_dst,
    short* __restrict__ hb, float* __restrict__ a_src_n,
    float* __restrict__ a_dst_n, int M)
{
    __shared__ short As[128][56];   // stride 112B: 16B-aligned rows, 2-way max bank alias
    const int t = threadIdx.x;
    const int lane = t & 63, wv = t >> 6;
    const int wr = wv >> 1, wc = wv & 1;
    const int quad = lane >> 4, l15 = lane & 15;
    const int m0 = blockIdx.x * 128;
    const int bn = blockIdx.y;
    const int hd = bn * 2 + wc;

    // staging map: thread t loads 16 floats of row sr, k-half skh
    const int sr = t >> 1, skh = (t & 1) * 16;
    const float* xrow = x + (size_t)(m0 + sr) * 256 + skh;
    const bool srow_ok = (m0 + sr) < M;

    const short* wbase = Wt + (size_t)(bn * 128 + wc * 64 + l15) * 256 + quad * 8;

    f4 acc[4][4];
#pragma unroll
    for (int i = 0; i < 4; ++i)
#pragma unroll
        for (int j = 0; j < 4; ++j) acc[i][j] = (f4)(0.f);

    for (int ks = 0; ks < 8; ++ks) {
        float4 v0 = {}, v1 = {}, v2 = {}, v3 = {};
        if (srow_ok) {
            const float4* p = (const float4*)(xrow + ks * 32);
            v0 = p[0]; v1 = p[1]; v2 = p[2]; v3 = p[3];
        }
        __syncthreads();
        short* dst = &As[sr][skh];
        dst[0]  = f2bf(v0.x); dst[1]  = f2bf(v0.y); dst[2]  = f2bf(v0.z); dst[3]  = f2bf(v0.w);
        dst[4]  = f2bf(v1.x); dst[5]  = f2bf(v1.y); dst[6]  = f2bf(v1.z); dst[7]  = f2bf(v1.w);
        dst[8]  = f2bf(v2.x); dst[9]  = f2bf(v2.y); dst[10] = f2bf(v2.z); dst[11] = f2bf(v2.w);
        dst[12] = f2bf(v3.x); dst[13] = f2bf(v3.y); dst[14] = f2bf(v3.z); dst[15] = f2bf(v3.w);
        __syncthreads();

        s8 af[4], bf[4];
#pragma unroll
        for (int i = 0; i < 4; ++i)
            af[i] = *(const s8*)&As[wr * 64 + i * 16 + l15][quad * 8];
#pragma unroll
        for (int j = 0; j < 4; ++j)
            bf[j] = *(const s8*)(wbase + (size_t)(j * 16) * 256 + ks * 32);
#pragma unroll
        for (int i = 0; i < 4; ++i)
#pragma unroll
            for (int j = 0; j < 4; ++j)
                acc[i][j] = __builtin_amdgcn_mfma_f32_16x16x32_bf16(af[i], bf[j], acc[i][j], 0, 0, 0);
    }

    // epilogue: bf16 store of h + fused per-head attention dots
    float asv[4], adv[4];
#pragma unroll
    for (int j = 0; j < 4; ++j) {
        asv[j] = att_src[hd * 64 + j * 16 + l15];
        adv[j] = att_dst[hd * 64 + j * 16 + l15];
    }
#pragma unroll
    for (int i = 0; i < 4; ++i) {
#pragma unroll
        for (int rr = 0; rr < 4; ++rr) {
            const int grow = m0 + wr * 64 + i * 16 + quad * 4 + rr;
            float ps = 0.f, pd = 0.f;
#pragma unroll
            for (int j = 0; j < 4; ++j) {
                float val = acc[i][j][rr];
                ps = fmaf(val, asv[j], ps);
                pd = fmaf(val, adv[j], pd);
                if (grow < M)
                    hb[(size_t)grow * 256 + bn * 128 + wc * 64 + j * 16 + l15] = f2bf(val);
            }
#pragma unroll
            for (int o = 1; o < 16; o <<= 1) {
                ps += __shfl_xor(ps, o);
                pd += __shfl_xor(pd, o);
            }
            if (l15 == 0 && grow < M) {
                a_src_n[grow * 4 + hd] = ps;
                a_dst_n[grow * 4 + hd] = pd;
            }
        }
    }
}

// ---------------------------------------------------------------------------
// Kernel 2: degree histogram over dst (edges + self loops)
// ---------------------------------------------------------------------------
__global__ void hist_kernel(const int* __restrict__ ei, int* __restrict__ deg,
                            int E, int N)
{
    int e = blockIdx.x * 256 + threadIdx.x;
    if (e >= E + N) return;
    int dte = (e < E) ? ei[E + e] : (e - E);
    atomicAdd(&deg[dte], 1);
}

// ---------------------------------------------------------------------------
// Kernels 3a/3b/3c: multi-block exclusive scan deg[N] -> off[N+1], cur[N]
// ---------------------------------------------------------------------------
__global__ __launch_bounds__(1024) void scan1(const int* __restrict__ deg,
                                              int* __restrict__ off,
                                              int* __restrict__ bsum, int N)
{
    __shared__ int wsum[16], wexc[16];
    const int t = threadIdx.x, lane = t & 63, w = t >> 6;
    const int idx = blockIdx.x * 1024 + t;
    int v = (idx < N) ? deg[idx] : 0;
    int val = v;
#pragma unroll
    for (int o = 1; o < 64; o <<= 1) {
        int u = __shfl_up(val, o);
        if (lane >= o) val += u;
    }
    if (lane == 63) wsum[w] = val;
    __syncthreads();
    if (t < 16) {
        int s = wsum[t];
#pragma unroll
        for (int o = 1; o < 16; o <<= 1) {
            int u = __shfl_up(s, o, 16);
            if (t >= o) s += u;
        }
        wexc[t] = s - wsum[t];
        if (t == 15) bsum[blockIdx.x] = s;
    }
    __syncthreads();
    if (idx < N) off[idx] = wexc[w] + val - v;
}

__global__ void scan2(const int* __restrict__ bsum, int* __restrict__ bexc,
                      int* __restrict__ off, int nb, int N)
{
    int t = threadIdx.x;  // 64 threads, nb <= 64
    int s = (t < nb) ? bsum[t] : 0;
    int val = s;
#pragma unroll
    for (int o = 1; o < 64; o <<= 1) {
        int u = __shfl_up(val, o);
        if (t >= o) val += u;
    }
    if (t < nb) bexc[t] = val - s;
    if (t == 63) off[N] = val;
}

__global__ __launch_bounds__(1024) void scan3(int* __restrict__ off,
                                              int* __restrict__ cur,
                                              const int* __restrict__ bexc, int N)
{
    int idx = blockIdx.x * 1024 + threadIdx.x;
    if (idx < N) {
        int o = off[idx] + bexc[blockIdx.x];
        off[idx] = o;
        cur[idx] = o;
    }
}

// ---------------------------------------------------------------------------
// Kernel 4: scatter edges into CSR by dst
// ---------------------------------------------------------------------------
__global__ void scatter_kernel(const int* __restrict__ ei, int* __restrict__ cur,
                               int* __restrict__ csr, int E, int N)
{
    int e = blockIdx.x * 256 + threadIdx.x;
    if (e >= E + N) return;
    int s, dte;
    if (e < E) { s = ei[e]; dte = ei[E + e]; }
    else       { s = e - E; dte = s; }
    int pos = atomicAdd(&cur[dte], 1);
    csr[pos] = s;
}

// ---------------------------------------------------------------------------
// Kernel 5: per-dst segment softmax + weighted aggregation + bias + relu.
// one wave per dst node; lane l owns channels 4l..4l+3 (head = l>>4).
// h gathered in bf16 (8B/lane, row = 512B, L2/L3 resident).
// ---------------------------------------------------------------------------
__global__ __launch_bounds__(256) void aggregate(const short* __restrict__ hb,
                                                 const float* __restrict__ a_src_n,
                                                 const float* __restrict__ a_dst_n,
                                                 const int* __restrict__ off,
                                                 const int* __restrict__ csr,
                                                 const float* __restrict__ bias,
                                                 float* __restrict__ out, int N)
{
    const int wv = threadIdx.x >> 6;
    const int lane = threadIdx.x & 63;
    const int n = blockIdx.x * 4 + wv;
    if (n >= N) return;

    const int base = off[n];
    const int d = off[n + 1] - base;
    const float4 ad = *(const float4*)(a_dst_n + 4 * n);

    // Phase A: per-head max of leaky(logit)
    float4 m = make_float4(-1e30f, -1e30f, -1e30f, -1e30f);
    for (int j = lane; j < d; j += 64) {
        int s = csr[base + j];
        float4 as = *(const float4*)(a_src_n + 4 * s);
        float lx = as.x + ad.x; lx = lx >= 0.f ? lx : NEG * lx;
        float ly = as.y + ad.y; ly = ly >= 0.f ? ly : NEG * ly;
        float lz = as.z + ad.z; lz = lz >= 0.f ? lz : NEG * lz;
        float lw = as.w + ad.w; lw = lw >= 0.f ? lw : NEG * lw;
        m.x = fmaxf(m.x, lx); m.y = fmaxf(m.y, ly);
        m.z = fmaxf(m.z, lz); m.w = fmaxf(m.w, lw);
    }
#pragma unroll
    for (int o = 32; o > 0; o >>= 1) {
        m.x = fmaxf(m.x, __shfl_xor(m.x, o));
        m.y = fmaxf(m.y, __shfl_xor(m.y, o));
        m.z = fmaxf(m.z, __shfl_xor(m.z, o));
        m.w = fmaxf(m.w, __shfl_xor(m.w, o));
    }

    // Phase B: sum of exp
    float4 sm = make_float4(0.f, 0.f, 0.f, 0.f);
    for (int j = lane; j < d; j += 64) {
        int s = csr[base + j];
        float4 as = *(const float4*)(a_src_n + 4 * s);
        float lx = as.x + ad.x; lx = lx >= 0.f ? lx : NEG * lx;
        float ly = as.y + ad.y; ly = ly >= 0.f ? ly : NEG * ly;
        float lz = as.z + ad.z; lz = lz >= 0.f ? lz : NEG * lz;
        float lw = as.w + ad.w; lw = lw >= 0.f ? lw : NEG * lw;
        sm.x += __expf(lx - m.x); sm.y += __expf(ly - m.y);
        sm.z += __expf(lz - m.z); sm.w += __expf(lw - m.w);
    }
#pragma unroll
    for (int o = 32; o > 0; o >>= 1) {
        sm.x += __shfl_xor(sm.x, o);
        sm.y += __shfl_xor(sm.y, o);
        sm.z += __shfl_xor(sm.z, o);
        sm.w += __shfl_xor(sm.w, o);
    }
    float4 inv = make_float4(1.f / (sm.x + 1e-16f), 1.f / (sm.y + 1e-16f),
                             1.f / (sm.z + 1e-16f), 1.f / (sm.w + 1e-16f));

    const int hl = lane >> 4;
    const float mh  = hl == 0 ? m.x  : hl == 1 ? m.y  : hl == 2 ? m.z  : m.w;
    const float ih  = hl == 0 ? inv.x: hl == 1 ? inv.y: hl == 2 ? inv.z: inv.w;
    const float adh = hl == 0 ? ad.x : hl == 1 ? ad.y : hl == 2 ? ad.z : ad.w;

    // Phase C: weighted accumulate of bf16 h[src] rows, 2x unrolled for MLP
    const ushort4* hp = (const ushort4*)hb;
    float4 a0 = make_float4(0.f, 0.f, 0.f, 0.f);
    float4 a1 = make_float4(0.f, 0.f, 0.f, 0.f);
    int j = 0;
    for (; j + 2 <= d; j += 2) {
        int s0 = csr[base + j], s1 = csr[base + j + 1];
        float g0 = a_src_n[4 * s0 + hl] + adh; g0 = g0 >= 0.f ? g0 : NEG * g0;
        float g1 = a_src_n[4 * s1 + hl] + adh; g1 = g1 >= 0.f ? g1 : NEG * g1;
        float w0 = __expf(g0 - mh) * ih;
        float w1 = __expf(g1 - mh) * ih;
        ushort4 h0 = hp[(size_t)s0 * 64 + lane];
        ushort4 h1 = hp[(size_t)s1 * 64 + lane];
        a0.x = fmaf(w0, bf2f(h0.x), a0.x); a0.y = fmaf(w0, bf2f(h0.y), a0.y);
        a0.z = fmaf(w0, bf2f(h0.z), a0.z); a0.w = fmaf(w0, bf2f(h0.w), a0.w);
        a1.x = fmaf(w1, bf2f(h1.x), a1.x); a1.y = fmaf(w1, bf2f(h1.y), a1.y);
        a1.z = fmaf(w1, bf2f(h1.z), a1.z); a1.w = fmaf(w1, bf2f(h1.w), a1.w);
    }
    if (j < d) {
        int s0 = csr[base + j];
        float g0 = a_src_n[4 * s0 + hl] + adh; g0 = g0 >= 0.f ? g0 : NEG * g0;
        float w0 = __expf(g0 - mh) * ih;
        ushort4 h0 = hp[(size_t)s0 * 64 + lane];
        a0.x = fmaf(w0, bf2f(h0.x), a0.x); a0.y = fmaf(w0, bf2f(h0.y), a0.y);
        a0.z = fmaf(w0, bf2f(h0.z), a0.z); a0.w = fmaf(w0, bf2f(h0.w), a0.w);
    }
    a0.x += a1.x; a0.y += a1.y; a0.z += a1.z; a0.w += a1.w;

    float4 b4 = *(const float4*)(bias + 4 * lane);
    float4 o4 = make_float4(fmaxf(a0.x + b4.x, 0.f), fmaxf(a0.y + b4.y, 0.f),
                            fmaxf(a0.z + b4.z, 0.f), fmaxf(a0.w + b4.w, 0.f));
    *(float4*)(out + (size_t)n * 256 + 4 * lane) = o4;
}

// ---------------------------------------------------------------------------
extern "C" void kernel_launch(void* const* d_in, const int* in_sizes, int n_in,
                              void* d_out, int out_size, void* d_ws, size_t ws_size,
                              hipStream_t stream)
{
    const float* x       = (const float*)d_in[0];
    const int*   ei      = (const int*)d_in[1];
    const float* W       = (const float*)d_in[2];
    const float* att_src = (const float*)d_in[3];
    const float* att_dst = (const float*)d_in[4];
    const float* bias    = (const float*)d_in[5];
    float* out = (float*)d_out;

    const int N = in_sizes[0] / 256;   // 50000
    const int E = in_sizes[1] / 2;     // 800000
    const int tot = E + N;
    const int nb = (N + 1023) / 1024;  // scan blocks (49)

    // workspace carve (~31 MB)
    char* p = (char*)d_ws;
    short* hb      = (short*)p;  p += (size_t)N * 256 * sizeof(short);
    short* Wt      = (short*)p;  p += 256 * 256 * sizeof(short);
    float* a_src_n = (float*)p;  p += (size_t)N * 4 * sizeof(float);
    float* a_dst_n = (float*)p;  p += (size_t)N * 4 * sizeof(float);
    int*   deg     = (int*)p;    p += (size_t)N * sizeof(int);
    int*   off     = (int*)p;    p += (size_t)(N + 1) * sizeof(int);
    int*   cur     = (int*)p;    p += (size_t)N * sizeof(int);
    int*   bsum    = (int*)p;    p += 64 * sizeof(int);
    int*   bexc    = (int*)p;    p += 64 * sizeof(int);
    int*   csr     = (int*)p;

    hipMemsetAsync(deg, 0, (size_t)N * sizeof(int), stream);
    cast_transpose_W<<<256, 256, 0, stream>>>(W, Wt);
    gemm_attn<<<dim3((N + 127) / 128, 2), 256, 0, stream>>>(
        x, Wt, att_src, att_dst, hb, a_src_n, a_dst_n, N);
    hist_kernel<<<(tot + 255) / 256, 256, 0, stream>>>(ei, deg, E, N);
    scan1<<<nb, 1024, 0, stream>>>(deg, off, bsum, N);
    scan2<<<1, 64, 0, stream>>>(bsum, bexc, off, nb, N);
    scan3<<<nb, 1024, 0, stream>>>(off, cur, bexc, N);
    scatter_kernel<<<(tot + 255) / 256, 256, 0, stream>>>(ei, cur, csr, E, N);
    aggregate<<<(N + 3) / 4, 256, 0, stream>>>(hb, a_src_n, a_dst_n, off, csr, bias, out, N);
}

// Round 3
// 301.338 us; speedup vs baseline: 1.6136x; 1.0700x over previous
//
#include <hip/hip_runtime.h>
#include <math.h>

#define NEG 0.2f

typedef __attribute__((ext_vector_type(4))) float f4;
typedef __attribute__((ext_vector_type(8))) short s8;

__device__ __forceinline__ short f2bf(float f) {
    unsigned u = __float_as_uint(f);
    u += 0x7fff + ((u >> 16) & 1);          // round-to-nearest-even
    return (short)(u >> 16);
}
__device__ __forceinline__ unsigned pk2(float a, float b) {
    return (unsigned)(unsigned short)f2bf(a) | ((unsigned)(unsigned short)f2bf(b) << 16);
}
__device__ __forceinline__ float bf2f(unsigned short s) {
    return __uint_as_float(((unsigned)s) << 16);
}

// ---------------------------------------------------------------------------
// Kernel 0: prep — Wt[n][k] = bf16(W[k][n])  +  deg[] = 0
// ---------------------------------------------------------------------------
__global__ void prep(const float* __restrict__ W, short* __restrict__ Wt,
                     int* __restrict__ deg, int N)
{
    int id = blockIdx.x * 256 + threadIdx.x;
    if (id < 65536) {
        int n = id >> 8, k = id & 255;
        Wt[id] = f2bf(W[k * 256 + n]);
    }
    if (id < N) deg[id] = 0;
}

// ---------------------------------------------------------------------------
// Kernel 1: MFMA GEMM computing h^T-layout: D[m=channel][n=node].
// A = Wt rows (channels, from global/L2), B = x rows (nodes, LDS-staged bf16).
// Lane holds 4 CONTIGUOUS channels of ONE node -> 8B hb stores, cheap dots.
// Block: 128 channels (grid.y*128 + wc*64 => head) x 128 nodes. 4 waves 2x2.
// ---------------------------------------------------------------------------
__global__ __launch_bounds__(256) void gemm_attn(
    const float* __restrict__ x, const short* __restrict__ Wt,
    const float* __restrict__ att_src, const float* __restrict__ att_dst,
    short* __restrict__ hb, float* __restrict__ a_src_n,
    float* __restrict__ a_dst_n, int M)
{
    __shared__ __align__(16) short xs[128][32];   // node-rows x 32 k (bf16)
    const int t = threadIdx.x;
    const int lane = t & 63, wv = t >> 6;
    const int wr = wv >> 1, wc = wv & 1;          // wr: node half, wc: channel half
    const int quad = lane >> 4, l15 = lane & 15;
    const int n0 = blockIdx.x * 128;              // node base
    const int bn = blockIdx.y;                    // channel block (128 ch)
    const int hd = bn * 2 + wc;                   // head of this wave

    // staging map: rep r in {0,1}: chunk = t + r*256 -> row=chunk>>2, kq=chunk&3
    const int row0 = t >> 2, kq0 = t & 3;
    const int row1 = (t + 256) >> 2, kq1 = (t + 256) & 3;
    const bool ok0 = (n0 + row0) < M, ok1 = (n0 + row1) < M;
    const float* xp0 = x + (size_t)(n0 + row0) * 256 + kq0 * 8;
    const float* xp1 = x + (size_t)(n0 + row1) * 256 + kq1 * 8;

    const short* wbase = Wt + (size_t)(bn * 128 + wc * 64 + l15) * 256 + quad * 8;

    f4 acc[4][4];   // [i: ch frag][j: node frag]
#pragma unroll
    for (int i = 0; i < 4; ++i)
#pragma unroll
        for (int j = 0; j < 4; ++j) acc[i][j] = (f4)(0.f);

    for (int ks = 0; ks < 8; ++ks) {
        float4 a0 = {}, a1 = {}, b0 = {}, b1 = {};
        if (ok0) { const float4* p = (const float4*)(xp0 + ks * 32); a0 = p[0]; a1 = p[1]; }
        if (ok1) { const float4* p = (const float4*)(xp1 + ks * 32); b0 = p[0]; b1 = p[1]; }
        __syncthreads();
        uint4 u0 = { pk2(a0.x, a0.y), pk2(a0.z, a0.w), pk2(a1.x, a1.y), pk2(a1.z, a1.w) };
        uint4 u1 = { pk2(b0.x, b0.y), pk2(b0.z, b0.w), pk2(b1.x, b1.y), pk2(b1.z, b1.w) };
        *(uint4*)&xs[row0][kq0 * 8] = u0;
        *(uint4*)&xs[row1][kq1 * 8] = u1;
        __syncthreads();

        s8 af[4], bf[4];
#pragma unroll
        for (int i = 0; i < 4; ++i)
            af[i] = *(const s8*)(wbase + (size_t)(i * 16) * 256 + ks * 32);
#pragma unroll
        for (int j = 0; j < 4; ++j)
            bf[j] = *(const s8*)&xs[wr * 64 + j * 16 + l15][quad * 8];
#pragma unroll
        for (int i = 0; i < 4; ++i)
#pragma unroll
            for (int j = 0; j < 4; ++j)
                acc[i][j] = __builtin_amdgcn_mfma_f32_16x16x32_bf16(af[i], bf[j], acc[i][j], 0, 0, 0);
    }

    // att vectors for this lane's channels: ch = hd*64 + i*16 + quad*4 + rr
    float asv[4][4], adv[4][4];
#pragma unroll
    for (int i = 0; i < 4; ++i)
#pragma unroll
        for (int rr = 0; rr < 4; ++rr) {
            asv[i][rr] = att_src[hd * 64 + i * 16 + quad * 4 + rr];
            adv[i][rr] = att_dst[hd * 64 + i * 16 + quad * 4 + rr];
        }

#pragma unroll
    for (int j = 0; j < 4; ++j) {
        const int node = n0 + wr * 64 + j * 16 + l15;
        const bool ok = node < M;
        float ps = 0.f, pd = 0.f;
#pragma unroll
        for (int i = 0; i < 4; ++i)
#pragma unroll
            for (int rr = 0; rr < 4; ++rr) {
                float v = acc[i][j][rr];
                ps = fmaf(v, asv[i][rr], ps);
                pd = fmaf(v, adv[i][rr], pd);
            }
        ps += __shfl_xor(ps, 16); ps += __shfl_xor(ps, 32);
        pd += __shfl_xor(pd, 16); pd += __shfl_xor(pd, 32);
        if (ok && quad == 0) {
            a_src_n[node * 4 + hd] = ps;
            a_dst_n[node * 4 + hd] = pd;
        }
        if (ok) {
#pragma unroll
            for (int i = 0; i < 4; ++i) {
                ushort4 pk;
                pk.x = (unsigned short)f2bf(acc[i][j][0]);
                pk.y = (unsigned short)f2bf(acc[i][j][1]);
                pk.z = (unsigned short)f2bf(acc[i][j][2]);
                pk.w = (unsigned short)f2bf(acc[i][j][3]);
                *(ushort4*)&hb[(size_t)node * 256 + hd * 64 + i * 16 + quad * 4] = pk;
            }
        }
    }
}

// ---------------------------------------------------------------------------
// Kernel 2: degree histogram over dst (edges + self loops)
// ---------------------------------------------------------------------------
__global__ void hist_kernel(const int* __restrict__ ei, int* __restrict__ deg,
                            int E, int N)
{
    int e = blockIdx.x * 256 + threadIdx.x;
    if (e >= E + N) return;
    int dte = (e < E) ? ei[E + e] : (e - E);
    atomicAdd(&deg[dte], 1);
}

// ---------------------------------------------------------------------------
// Kernels 3a/3b/3c: multi-block exclusive scan deg[N] -> off[N+1], cur[N]
// ---------------------------------------------------------------------------
__global__ __launch_bounds__(1024) void scan1(const int* __restrict__ deg,
                                              int* __restrict__ off,
                                              int* __restrict__ bsum, int N)
{
    __shared__ int wsum[16], wexc[16];
    const int t = threadIdx.x, lane = t & 63, w = t >> 6;
    const int idx = blockIdx.x * 1024 + t;
    int v = (idx < N) ? deg[idx] : 0;
    int val = v;
#pragma unroll
    for (int o = 1; o < 64; o <<= 1) {
        int u = __shfl_up(val, o);
        if (lane >= o) val += u;
    }
    if (lane == 63) wsum[w] = val;
    __syncthreads();
    if (t < 16) {
        int s = wsum[t];
#pragma unroll
        for (int o = 1; o < 16; o <<= 1) {
            int u = __shfl_up(s, o, 16);
            if (t >= o) s += u;
        }
        wexc[t] = s - wsum[t];
        if (t == 15) bsum[blockIdx.x] = s;
    }
    __syncthreads();
    if (idx < N) off[idx] = wexc[w] + val - v;
}

__global__ void scan2(const int* __restrict__ bsum, int* __restrict__ bexc,
                      int* __restrict__ off, int nb, int N)
{
    int t = threadIdx.x;  // 64 threads, nb <= 64
    int s = (t < nb) ? bsum[t] : 0;
    int val = s;
#pragma unroll
    for (int o = 1; o < 64; o <<= 1) {
        int u = __shfl_up(val, o);
        if (t >= o) val += u;
    }
    if (t < nb) bexc[t] = val - s;
    if (t == 63) off[N] = val;
}

__global__ __launch_bounds__(1024) void scan3(int* __restrict__ off,
                                              int* __restrict__ cur,
                                              const int* __restrict__ bexc, int N)
{
    int idx = blockIdx.x * 1024 + threadIdx.x;
    if (idx < N) {
        int o = off[idx] + bexc[blockIdx.x];
        off[idx] = o;
        cur[idx] = o;
    }
}

// ---------------------------------------------------------------------------
// Kernel 4: scatter edges into CSR by dst
// ---------------------------------------------------------------------------
__global__ void scatter_kernel(const int* __restrict__ ei, int* __restrict__ cur,
                               int* __restrict__ csr, int E, int N)
{
    int e = blockIdx.x * 256 + threadIdx.x;
    if (e >= E + N) return;
    int s, dte;
    if (e < E) { s = ei[e]; dte = ei[E + e]; }
    else       { s = e - E; dte = s; }
    int pos = atomicAdd(&cur[dte], 1);
    csr[pos] = s;
}

// ---------------------------------------------------------------------------
// Kernel 5: segment softmax + aggregation, producer/consumer within each wave.
// One wave per dst. Chunk of 64 edges: lane j computes UN-NORMALIZED weight
// for edge j (all 4 heads) once -> LDS; consumer reads weight via LDS
// broadcast + src id via readlane, gathers bf16 h row (coalesced 512B).
// No max pass (logits bounded ~8, exp safe in fp32; alpha identical).
// Normalization applied once at the end.
// ---------------------------------------------------------------------------
__global__ __launch_bounds__(256) void aggregate(const short* __restrict__ hb,
                                                 const float* __restrict__ a_src_n,
                                                 const float* __restrict__ a_dst_n,
                                                 const int* __restrict__ off,
                                                 const int* __restrict__ csr,
                                                 const float* __restrict__ bias,
                                                 float* __restrict__ out, int N)
{
    __shared__ float lds_w[4][64][4];
    const int wv = threadIdx.x >> 6;
    const int lane = threadIdx.x & 63;
    const int n = blockIdx.x * 4 + wv;
    if (n >= N) return;

    const int base = off[n];
    const int d = off[n + 1] - base;
    const float4 ad = *(const float4*)(a_dst_n + 4 * n);
    const int hl = lane >> 4;

    float4 sum = make_float4(0.f, 0.f, 0.f, 0.f);
    float4 accA = make_float4(0.f, 0.f, 0.f, 0.f);
    float4 accB = make_float4(0.f, 0.f, 0.f, 0.f);
    const ushort4* hp = (const ushort4*)hb;

    for (int c0 = 0; c0 < d; c0 += 64) {
        int j = c0 + lane;
        int s = 0;
        float4 w4 = make_float4(0.f, 0.f, 0.f, 0.f);
        if (j < d) {
            s = csr[base + j];
            float4 as = *(const float4*)(a_src_n + 4 * s);
            float lx = as.x + ad.x; lx = lx >= 0.f ? lx : NEG * lx;
            float ly = as.y + ad.y; ly = ly >= 0.f ? ly : NEG * ly;
            float lz = as.z + ad.z; lz = lz >= 0.f ? lz : NEG * lz;
            float lw = as.w + ad.w; lw = lw >= 0.f ? lw : NEG * lw;
            w4 = make_float4(__expf(lx), __expf(ly), __expf(lz), __expf(lw));
        }
        sum.x += w4.x; sum.y += w4.y; sum.z += w4.z; sum.w += w4.w;
        *(float4*)&lds_w[wv][lane][0] = w4;
        __builtin_amdgcn_wave_barrier();

        const int cl = (d - c0) < 64 ? (d - c0) : 64;
        int jj = 0;
        for (; jj + 2 <= cl; jj += 2) {
            int s0 = __builtin_amdgcn_readlane(s, jj);
            int s1 = __builtin_amdgcn_readlane(s, jj + 1);
            float w0 = lds_w[wv][jj][hl];
            float w1 = lds_w[wv][jj + 1][hl];
            ushort4 h0 = hp[(size_t)s0 * 64 + lane];
            ushort4 h1 = hp[(size_t)s1 * 64 + lane];
            accA.x = fmaf(w0, bf2f(h0.x), accA.x); accA.y = fmaf(w0, bf2f(h0.y), accA.y);
            accA.z = fmaf(w0, bf2f(h0.z), accA.z); accA.w = fmaf(w0, bf2f(h0.w), accA.w);
            accB.x = fmaf(w1, bf2f(h1.x), accB.x); accB.y = fmaf(w1, bf2f(h1.y), accB.y);
            accB.z = fmaf(w1, bf2f(h1.z), accB.z); accB.w = fmaf(w1, bf2f(h1.w), accB.w);
        }
        if (jj < cl) {
            int s0 = __builtin_amdgcn_readlane(s, jj);
            float w0 = lds_w[wv][jj][hl];
            ushort4 h0 = hp[(size_t)s0 * 64 + lane];
            accA.x = fmaf(w0, bf2f(h0.x), accA.x); accA.y = fmaf(w0, bf2f(h0.y), accA.y);
            accA.z = fmaf(w0, bf2f(h0.z), accA.z); accA.w = fmaf(w0, bf2f(h0.w), accA.w);
        }
        __builtin_amdgcn_wave_barrier();
    }

    accA.x += accB.x; accA.y += accB.y; accA.z += accB.z; accA.w += accB.w;

#pragma unroll
    for (int o = 32; o > 0; o >>= 1) {
        sum.x += __shfl_xor(sum.x, o);
        sum.y += __shfl_xor(sum.y, o);
        sum.z += __shfl_xor(sum.z, o);
        sum.w += __shfl_xor(sum.w, o);
    }
    float sh = (hl & 2) ? ((hl & 1) ? sum.w : sum.z) : ((hl & 1) ? sum.y : sum.x);
    float ih = 1.f / (sh + 1e-16f);

    float4 b4 = *(const float4*)(bias + 4 * lane);
    float4 o4;
    o4.x = fmaxf(fmaf(accA.x, ih, b4.x), 0.f);
    o4.y = fmaxf(fmaf(accA.y, ih, b4.y), 0.f);
    o4.z = fmaxf(fmaf(accA.z, ih, b4.z), 0.f);
    o4.w = fmaxf(fmaf(accA.w, ih, b4.w), 0.f);
    *(float4*)(out + (size_t)n * 256 + 4 * lane) = o4;
}

// ---------------------------------------------------------------------------
extern "C" void kernel_launch(void* const* d_in, const int* in_sizes, int n_in,
                              void* d_out, int out_size, void* d_ws, size_t ws_size,
                              hipStream_t stream)
{
    const float* x       = (const float*)d_in[0];
    const int*   ei      = (const int*)d_in[1];
    const float* W       = (const float*)d_in[2];
    const float* att_src = (const float*)d_in[3];
    const float* att_dst = (const float*)d_in[4];
    const float* bias    = (const float*)d_in[5];
    float* out = (float*)d_out;

    const int N = in_sizes[0] / 256;   // 50000
    const int E = in_sizes[1] / 2;     // 800000
    const int tot = E + N;
    const int nb = (N + 1023) / 1024;  // scan blocks (49)

    // workspace carve (~31 MB)
    char* p = (char*)d_ws;
    short* hb      = (short*)p;  p += (size_t)N * 256 * sizeof(short);
    short* Wt      = (short*)p;  p += 256 * 256 * sizeof(short);
    float* a_src_n = (float*)p;  p += (size_t)N * 4 * sizeof(float);
    float* a_dst_n = (float*)p;  p += (size_t)N * 4 * sizeof(float);
    int*   deg     = (int*)p;    p += (size_t)N * sizeof(int);
    int*   off     = (int*)p;    p += (size_t)(N + 1) * sizeof(int);
    int*   cur     = (int*)p;    p += (size_t)N * sizeof(int);
    int*   bsum    = (int*)p;    p += 64 * sizeof(int);
    int*   bexc    = (int*)p;    p += 64 * sizeof(int);
    int*   csr     = (int*)p;

    int prep_items = N > 65536 ? N : 65536;
    prep<<<(prep_items + 255) / 256, 256, 0, stream>>>(W, Wt, deg, N);
    gemm_attn<<<dim3((N + 127) / 128, 2), 256, 0, stream>>>(
        x, Wt, att_src, att_dst, hb, a_src_n, a_dst_n, N);
    hist_kernel<<<(tot + 255) / 256, 256, 0, stream>>>(ei, deg, E, N);
    scan1<<<nb, 1024, 0, stream>>>(deg, off, bsum, N);
    scan2<<<1, 64, 0, stream>>>(bsum, bexc, off, nb, N);
    scan3<<<nb, 1024, 0, stream>>>(off, cur, bexc, N);
    scatter_kernel<<<(tot + 255) / 256, 256, 0, stream>>>(ei, cur, csr, E, N);
    aggregate<<<(N + 3) / 4, 256, 0, stream>>>(hb, a_src_n, a_dst_n, off, csr, bias, out, N);
}